// Round 1
// 650.584 us; speedup vs baseline: 1.2100x; 1.2100x over previous
//
#include <hip/hip_runtime.h>
#include <hip/hip_bf16.h>
#include <stdint.h>

// Cross-attention: out = softmax((X Wq)(C Wk)^T / sqrt(D)) (C Wv) Wo
// GEMMs: 256x256 tile, BK=64, 8 waves (2x4), deep-pipelined 4-phase schedule:
//  - 2x double-buffered 32KB A/B LDS tiles (128 KiB total, dynamic LDS)
//  - global_load_lds(16B) staging, issues split ph1/ph4 at earliest region-legal
//    slot -> every chunk has >=4 phases of issue->consume slack
//  - counted s_waitcnt vmcnt(8) once per K-tile (never drains in main loop)
//  - raw s_barrier (NOT __syncthreads -> avoids compiler vmcnt(0) drain)
//  - st_16x32 LDS swizzle (byte ^= ((byte>>9)&1)<<5) applied on the global
//    source during staging and on ds_read addresses (both-sides involution)
//  - s_setprio(1) around each 16-MFMA cluster
//  - XCD-aware 1D tile remap kept (gid%8 = XCD on MI355X).

typedef __bf16 bf16;
typedef __attribute__((ext_vector_type(8))) __bf16 bf16x8;
typedef __attribute__((ext_vector_type(4))) float f32x4;

__device__ __forceinline__ void g2lds16(const void* g, void* l) {
    __builtin_amdgcn_global_load_lds(
        (__attribute__((address_space(1))) void*)g,
        (__attribute__((address_space(3))) void*)l,
        16, 0, 0);
}

// LDS layout (bytes): A-buf0 [0,32K) A-buf1 [32K,64K) B-buf0 [64K,96K) B-buf1 [96K,128K)
#define ABUF(p) ((p) * 32768)
#define BBUF(p) (65536 + (p) * 32768)

// Stage one 64-row chunk c (8KB) of a [256][64]-bf16 tile.
// LDS dest is linear (base + t*16, global_load_lds constraint); the swizzle is
// realized by permuting the per-lane GLOBAL source column:
//   phys byte b holds logical col (b&127) ^ (((b>>9)&1)<<5)   [bit9 = row bit2]
__device__ __forceinline__ void stage_chunk(
    const bf16* __restrict__ gsrc, int ld, char* ldsbuf, int c,
    int tr, int colElem, int t)
{
    g2lds16(gsrc + (long)(c * 64 + tr) * ld + colElem,
            ldsbuf + c * 8192 + t * 16);
}

// C[m][n] = scale * sum_k A[m][k] * Bt[n][k]; A:[M,K] lda, Bt:[N,K] ldb, C:[M,N] ldc.
// 1D grid with XCD remap; gx = N/256 tiles, gy = M/256 tiles, batches via strides.
template <bool BF16OUT>
__global__ __launch_bounds__(512) void gemm_bt(
    const bf16* __restrict__ A, const bf16* __restrict__ Bt, void* __restrict__ Cv,
    int K, int lda, int ldb, int ldc,
    long sA, long sB, long sC, float scale,
    int gx, int gy, int rowsPerXcd)
{
    extern __shared__ __align__(16) char lds[];

    const int gid  = blockIdx.x;
    const int xcd  = gid & 7;
    const int slot = gid >> 3;
    const int tx   = slot % gx;
    const int rw   = xcd * rowsPerXcd + slot / gx;
    const int ty   = rw % gy;
    const int z    = rw / gy;

    A  += (long)z * sA;
    Bt += (long)z * sB;

    const int t  = threadIdx.x;
    const int wv = t >> 6, lane = t & 63;
    const int wm = wv >> 2, wn = wv & 3;     // 2x4 wave grid: 128x64 out each
    const int lm = lane & 15, lk = lane >> 4;

    const long by = (long)ty * 256;
    const long bx = (long)tx * 256;

    const bf16* Ab = A  + by * (long)lda;    // tile origin (col advances 64/K-tile)
    const bf16* Bb = Bt + bx * (long)ldb;

    // staging per-thread constants: thread t covers row c*64 + (t>>3),
    // source col pre-swizzled (involution key = dest bit9 = (t>>5)&1)
    const int tr      = t >> 3;
    const int colElem = ((t & 7) * 8) ^ (((t >> 5) & 1) * 16);

    // ds_read base byte offsets (swizzle key = row bit2 = lm bit2, flips byte bit5)
    const int lkx   = (lk * 16) ^ ((lm & 4) << 3);
    const int aOff0 = (wm * 128 + lm) * 128 + lkx;
    const int bOff0 = (wn * 64  + lm) * 128 + lkx;

    f32x4 acc[8][4] = {};
    const int NT = K >> 6;

    // ---- prologue: issue order mimics steady-state stream so vmcnt counts hold
    // [~iter-2 ph4]: A-ih0(0) {0,2}, B-lo(0) {0,1}
    stage_chunk(Ab, lda, lds + ABUF(0), 0, tr, colElem, t);
    stage_chunk(Ab, lda, lds + ABUF(0), 2, tr, colElem, t);
    stage_chunk(Bb, ldb, lds + BBUF(0), 0, tr, colElem, t);
    stage_chunk(Bb, ldb, lds + BBUF(0), 1, tr, colElem, t);
    // [~iter-1 ph1]: B-hi(0) {2,3}, A-ih1(0) {1,3}
    stage_chunk(Bb, ldb, lds + BBUF(0), 2, tr, colElem, t);
    stage_chunk(Bb, ldb, lds + BBUF(0), 3, tr, colElem, t);
    stage_chunk(Ab, lda, lds + ABUF(0), 1, tr, colElem, t);
    stage_chunk(Ab, lda, lds + ABUF(0), 3, tr, colElem, t);
    // [~iter-1 ph4]: A-ih0(1), B-lo(1)
    if (NT > 1) {
        stage_chunk(Ab + 64, lda, lds + ABUF(1), 0, tr, colElem, t);
        stage_chunk(Ab + 64, lda, lds + ABUF(1), 2, tr, colElem, t);
        stage_chunk(Bb + 64, ldb, lds + BBUF(1), 0, tr, colElem, t);
        stage_chunk(Bb + 64, ldb, lds + BBUF(1), 1, tr, colElem, t);
    }

    for (int u = 0; u < NT; ++u) {
        char* aC = lds + ABUF(u & 1);
        char* bC = lds + BBUF(u & 1);
        bf16x8 af[4], bfr[4];

        // ---------- phase 1: stage B-hi(u+1)+A-ih1(u+1); MFMA i0-3 x j0-3, kk0
        if (u + 1 < NT) {
            const bf16* An = Ab + (u + 1) * 64;
            const bf16* Bn = Bb + (u + 1) * 64;
            char* aN = lds + ABUF((u + 1) & 1);
            char* bN = lds + BBUF((u + 1) & 1);
            stage_chunk(Bn, ldb, bN, 2, tr, colElem, t);   // regions last read @u-1,
            stage_chunk(Bn, ldb, bN, 3, tr, colElem, t);   // barrier'd since
            stage_chunk(An, lda, aN, 1, tr, colElem, t);
            stage_chunk(An, lda, aN, 3, tr, colElem, t);
            // allow newest 8 (this ph1 + prev ph4) in flight; tile u is older -> landed
            asm volatile("s_waitcnt vmcnt(8)" ::: "memory");
        } else {
            asm volatile("s_waitcnt vmcnt(0)" ::: "memory");  // tail only; loads are old
        }
        __builtin_amdgcn_s_barrier();
        asm volatile("" ::: "memory");

        #pragma unroll
        for (int i = 0; i < 4; ++i)
            af[i] = *(const bf16x8*)(aC + aOff0 + i * 2048);
        #pragma unroll
        for (int j = 0; j < 4; ++j)
            bfr[j] = *(const bf16x8*)(bC + bOff0 + j * 2048);
        asm volatile("s_waitcnt lgkmcnt(0)" ::: "memory");
        __builtin_amdgcn_s_setprio(1);
        #pragma unroll
        for (int i = 0; i < 4; ++i)
            #pragma unroll
            for (int j = 0; j < 4; ++j)
                acc[i][j] = __builtin_amdgcn_mfma_f32_16x16x32_bf16(
                    af[i], bfr[j], acc[i][j], 0, 0, 0);
        __builtin_amdgcn_s_setprio(0);
        asm volatile("" ::: "memory");
        __builtin_amdgcn_s_barrier();
        asm volatile("" ::: "memory");

        // ---------- phase 2: MFMA i4-7 x j0-3, kk0 (b regs reused)
        #pragma unroll
        for (int i = 0; i < 4; ++i)
            af[i] = *(const bf16x8*)(aC + aOff0 + (i + 4) * 2048);
        asm volatile("s_waitcnt lgkmcnt(0)" ::: "memory");
        __builtin_amdgcn_s_setprio(1);
        #pragma unroll
        for (int i = 0; i < 4; ++i)
            #pragma unroll
            for (int j = 0; j < 4; ++j)
                acc[i + 4][j] = __builtin_amdgcn_mfma_f32_16x16x32_bf16(
                    af[i], bfr[j], acc[i + 4][j], 0, 0, 0);
        __builtin_amdgcn_s_setprio(0);
        asm volatile("" ::: "memory");
        __builtin_amdgcn_s_barrier();
        asm volatile("" ::: "memory");

        // ---------- phase 3: MFMA i0-3 x j0-3, kk1
        #pragma unroll
        for (int i = 0; i < 4; ++i)
            af[i] = *(const bf16x8*)(aC + aOff0 + i * 2048 + 64);
        #pragma unroll
        for (int j = 0; j < 4; ++j)
            bfr[j] = *(const bf16x8*)(bC + bOff0 + j * 2048 + 64);
        asm volatile("s_waitcnt lgkmcnt(0)" ::: "memory");
        __builtin_amdgcn_s_setprio(1);
        #pragma unroll
        for (int i = 0; i < 4; ++i)
            #pragma unroll
            for (int j = 0; j < 4; ++j)
                acc[i][j] = __builtin_amdgcn_mfma_f32_16x16x32_bf16(
                    af[i], bfr[j], acc[i][j], 0, 0, 0);
        __builtin_amdgcn_s_setprio(0);
        asm volatile("" ::: "memory");
        __builtin_amdgcn_s_barrier();
        asm volatile("" ::: "memory");

        // ---------- phase 4: stage A-ih0(u+2)+B-lo(u+2); MFMA i4-7 x j0-3, kk1
        #pragma unroll
        for (int i = 0; i < 4; ++i)
            af[i] = *(const bf16x8*)(aC + aOff0 + (i + 4) * 2048 + 64);
        if (u + 2 < NT) {
            const bf16* An = Ab + (u + 2) * 64;
            const bf16* Bn = Bb + (u + 2) * 64;
            // same-parity buffer: chunks {0,2}A/{0,1}B were last read in ph1-3,
            // ph3-end barrier passed; ph4 reads only A chunks {1,3} -> disjoint
            stage_chunk(An, lda, aC, 0, tr, colElem, t);
            stage_chunk(An, lda, aC, 2, tr, colElem, t);
            stage_chunk(Bn, ldb, bC, 0, tr, colElem, t);
            stage_chunk(Bn, ldb, bC, 1, tr, colElem, t);
        }
        asm volatile("s_waitcnt lgkmcnt(0)" ::: "memory");
        __builtin_amdgcn_s_setprio(1);
        #pragma unroll
        for (int i = 0; i < 4; ++i)
            #pragma unroll
            for (int j = 0; j < 4; ++j)
                acc[i + 4][j] = __builtin_amdgcn_mfma_f32_16x16x32_bf16(
                    af[i], bfr[j], acc[i + 4][j], 0, 0, 0);
        __builtin_amdgcn_s_setprio(0);
        asm volatile("" ::: "memory");
        __builtin_amdgcn_s_barrier();
        asm volatile("" ::: "memory");
    }

    // epilogue: C/D layout col=lane&15, row=(lane>>4)*4+reg (m89-verified)
    const long r0 = by + wm * 128 + lk * 4;
    const long c0 = bx + wn * 64 + lm;
    if (BF16OUT) {
        bf16* C = (bf16*)Cv + (long)z * sC;
        #pragma unroll
        for (int i = 0; i < 8; ++i) {
            const long rb = r0 + i * 16;
            #pragma unroll
            for (int j = 0; j < 4; ++j) {
                const long cc = c0 + j * 16;
                #pragma unroll
                for (int r = 0; r < 4; ++r)
                    C[(rb + r) * (long)ldc + cc] = (bf16)(acc[i][j][r] * scale);
            }
        }
    } else {
        float* C = (float*)Cv + (long)z * sC;
        #pragma unroll
        for (int i = 0; i < 8; ++i) {
            const long rb = r0 + i * 16;
            #pragma unroll
            for (int j = 0; j < 4; ++j) {
                const long cc = c0 + j * 16;
                #pragma unroll
                for (int r = 0; r < 4; ++r)
                    C[(rb + r) * (long)ldc + cc] = acc[i][j][r] * scale;
            }
        }
    }
}

__global__ __launch_bounds__(256) void f32_to_bf16_k(
    const float* __restrict__ in, bf16* __restrict__ out, long n)
{
    long i = ((long)blockIdx.x * blockDim.x + threadIdx.x) * 8;
    if (i + 8 > n) return;
    const float4* p = (const float4*)(in + i);
    float4 a = p[0], b = p[1];
    bf16x8 o = { (bf16)a.x, (bf16)a.y, (bf16)a.z, (bf16)a.w,
                 (bf16)b.x, (bf16)b.y, (bf16)b.z, (bf16)b.w };
    *(bf16x8*)(out + i) = o;
}

// out[c][r] = in[r][c]; in [R,C] -> out [C,R]; R,C % 32 == 0
template <typename Tin>
__global__ __launch_bounds__(256) void transpose_to_bf16(
    const Tin* __restrict__ in, bf16* __restrict__ out,
    int R, int C, long sIn, long sOut)
{
    __shared__ bf16 tile[32][33];
    in  += (long)blockIdx.z * sIn;
    out += (long)blockIdx.z * sOut;
    const int bx = blockIdx.x * 32, by = blockIdx.y * 32;
    const int tx = threadIdx.x, ty = threadIdx.y;
    #pragma unroll
    for (int r = ty; r < 32; r += 8)
        tile[r][tx] = (bf16)in[(long)(by + r) * C + bx + tx];
    __syncthreads();
    #pragma unroll
    for (int r = ty; r < 32; r += 8)
        out[(long)(bx + r) * R + by + tx] = tile[tx][r];
}

// one block per row of n=2048; in-place fp32 softmax + bf16 copy
__global__ __launch_bounds__(256) void softmax_rows(
    float* __restrict__ sc, bf16* __restrict__ wbf, int n)
{
    const long base = (long)blockIdx.x * n;
    const int t = threadIdx.x;
    const int wave = t >> 6, lane = t & 63;
    float v[8];
    #pragma unroll
    for (int k = 0; k < 8; ++k) v[k] = sc[base + t + k * 256];

    float m = v[0];
    #pragma unroll
    for (int k = 1; k < 8; ++k) m = fmaxf(m, v[k]);
    #pragma unroll
    for (int off = 32; off; off >>= 1) m = fmaxf(m, __shfl_xor(m, off, 64));
    __shared__ float red[4];
    if (lane == 0) red[wave] = m;
    __syncthreads();
    m = fmaxf(fmaxf(red[0], red[1]), fmaxf(red[2], red[3]));

    float s = 0.f;
    #pragma unroll
    for (int k = 0; k < 8; ++k) { v[k] = __expf(v[k] - m); s += v[k]; }
    #pragma unroll
    for (int off = 32; off; off >>= 1) s += __shfl_xor(s, off, 64);
    __syncthreads();
    if (lane == 0) red[wave] = s;
    __syncthreads();
    s = red[0] + red[1] + red[2] + red[3];
    const float inv = 1.0f / s;
    #pragma unroll
    for (int k = 0; k < 8; ++k) {
        float w = v[k] * inv;
        sc[base + t + k * 256]  = w;
        wbf[base + t + k * 256] = (bf16)w;
    }
}

extern "C" void kernel_launch(void* const* d_in, const int* in_sizes, int n_in,
                              void* d_out, int out_size, void* d_ws, size_t ws_size,
                              hipStream_t stream)
{
    const int Bb = 8, S = 2048, D = 1024;
    const long BSD = (long)Bb * S * D;   // 16,777,216
    const long DD  = (long)D * D;

    const float* input   = (const float*)d_in[0];
    const float* context = (const float*)d_in[1];
    const float* Wq = (const float*)d_in[2];
    const float* Wk = (const float*)d_in[3];
    const float* Wv = (const float*)d_in[4];
    const float* Wo = (const float*)d_in[5];

    // workspace layout (bf16 elements), ~176 MB with aliasing:
    bf16* Xbf = (bf16*)d_ws;        // input bf16  [16384,1024]   (later: ctx)
    bf16* Cbf = Xbf + BSD;          // context bf16               (later: Wbf lo)
    bf16* Kbf = Cbf + BSD;          // K bf16                     (later: Wbf hi)
    bf16* Qbf = Kbf + BSD;          // Q bf16
    bf16* VT  = Qbf + BSD;          // V^T bf16 [B,1024,2048]
    bf16* WqT = VT + BSD;           // weights transposed [N,K] bf16
    bf16* WkT = WqT + DD;
    bf16* WvT = WkT + DD;
    bf16* WoT = WvT + DD;
    bf16* ctxb = Xbf;               // alias: Xbf dead after Q projection
    bf16* Wbf  = Cbf;               // alias: Cbf+Kbf dead after scores; spans 2*BSD

    float* outp   = (float*)d_out;
    float* scores = outp + BSD;     // weights region used as scores scratch (in-place)

    const dim3 blk256(256);
    const dim3 blk512(512);
    const dim3 tb(32, 8);
    const int LDSZ = 131072;        // 128 KiB dynamic LDS for gemm_bt

    static bool attrDone = false;
    if (!attrDone) {
        hipFuncSetAttribute((const void*)gemm_bt<true>,
                            hipFuncAttributeMaxDynamicSharedMemorySize, LDSZ);
        hipFuncSetAttribute((const void*)gemm_bt<false>,
                            hipFuncAttributeMaxDynamicSharedMemorySize, LDSZ);
        attrDone = true;
    }

    // 1. fp32 -> bf16 converts
    f32_to_bf16_k<<<dim3((unsigned)(BSD / 8 / 256)), blk256, 0, stream>>>(input,   Xbf, BSD);
    f32_to_bf16_k<<<dim3((unsigned)(BSD / 8 / 256)), blk256, 0, stream>>>(context, Cbf, BSD);

    // 2. weight transpose+convert: [K,N] fp32 -> [N,K] bf16
    transpose_to_bf16<float><<<dim3(32, 32, 1), tb, 0, stream>>>(Wq, WqT, D, D, 0, 0);
    transpose_to_bf16<float><<<dim3(32, 32, 1), tb, 0, stream>>>(Wk, WkT, D, D, 0, 0);
    transpose_to_bf16<float><<<dim3(32, 32, 1), tb, 0, stream>>>(Wv, WvT, D, D, 0, 0);
    transpose_to_bf16<float><<<dim3(32, 32, 1), tb, 0, stream>>>(Wo, WoT, D, D, 0, 0);

    // 3. projections (batch-merged M=16384): gx=4, gy=64, grid=256, rpx=8
    gemm_bt<true><<<dim3(256), blk512, LDSZ, stream>>>(
        Xbf, WqT, Qbf, D, D, D, D, 0, 0, 0, 1.0f, 4, 64, 8);
    gemm_bt<true><<<dim3(256), blk512, LDSZ, stream>>>(
        Cbf, WkT, Kbf, D, D, D, D, 0, 0, 0, 1.0f, 4, 64, 8);
    // V^T directly: VT[e][s] = sum_k WvT[e][k] * Cbf[s][k]; gx=8, gy=4, z=8 -> rpx=4
    gemm_bt<true><<<dim3(256), blk512, LDSZ, stream>>>(
        WvT, Cbf, VT, D, D, D, S, 0, (long)S * D, (long)D * S, 1.0f, 8, 4, 4);

    // 4. scores = Q K^T / 32 -> fp32; gx=8, gy=8, z=8, grid=512, rpx=8
    gemm_bt<false><<<dim3(512), blk512, LDSZ, stream>>>(
        Qbf, Kbf, scores, D, D, D, S,
        (long)S * D, (long)S * D, (long)S * S, 0.03125f, 8, 8, 8);

    // 5. softmax in place + bf16 copy
    softmax_rows<<<dim3(Bb * S), blk256, 0, stream>>>(scores, Wbf, S);

    // 6. ctx = W V; gx=4, gy=8, z=8, grid=256, rpx=8
    gemm_bt<true><<<dim3(256), blk512, LDSZ, stream>>>(
        Wbf, VT, ctxb, S, S, S, D,
        (long)S * S, (long)D * S, (long)S * D, 1.0f, 4, 8, 8);

    // 7. output = ctx Wo -> fp32 d_out; gx=4, gy=64, grid=256, rpx=8
    gemm_bt<false><<<dim3(256), blk512, LDSZ, stream>>>(
        ctxb, WoT, outp, D, D, D, D, 0, 0, 0, 1.0f, 4, 64, 8);
}